// Round 4
// baseline (1285.615 us; speedup 1.0000x reference)
//
#include <hip/hip_runtime.h>
#include <hip/hip_bf16.h>

#define EPS_ODIN 0.0014f

constexpr int Bb  = 1024;
constexpr int Cc  = 100;
constexpr int Dd  = 512;
constexpr int INn = 3072;
constexpr int NBLK = 512;
constexpr int NTHR = 256;
constexpr int PITCH = 68;   // shorts; 136B pitch -> benign 2-way conflicts on b128

using s16x8 = __attribute__((ext_vector_type(8))) short;
using s16x4 = __attribute__((ext_vector_type(4))) short;
using f32x4 = __attribute__((ext_vector_type(4))) float;

__device__ __forceinline__ short f2bf(float f) {
    __hip_bfloat16 h = __float2bfloat16(f);
    return *reinterpret_cast<short*>(&h);
}
__device__ __forceinline__ float bf2f(short s) {
    __hip_bfloat16 h;
    *reinterpret_cast<short*>(&h) = s;
    return __bfloat162float(h);
}

struct SMemG { short As[2][128 * PITCH]; short Bs[2][64 * PITCH]; };
struct SMemT { short Hs[2][64 * PITCH]; short Ms[2][112 * PITCH]; float srow[64]; int cst[64]; };
struct SMemR { float tp[32][33]; float red[4]; };
union  SMem  { SMemG g; SMemT t; SMemR r; };

// ---- workspace layout (barrier at 0, data from 256) ----
#define OFF_XH   ((size_t)256)
#define OFF_XL   (OFF_XH  + 6291456)
#define OFF_WTH  (OFF_XL  + 6291456)
#define OFF_WTL  (OFF_WTH + 3145728)
#define OFF_WH   (OFF_WTL + 3145728)
#define OFF_WL   (OFF_WH  + 3145728)
#define OFF_ISH  (OFF_WL  + 3145728)
#define OFF_ISL  (OFF_ISH + 524288)
#define OFF_MUH  (OFF_ISL + 524288)
#define OFF_MUL  (OFF_MUH + 102400)
#define OFF_IM   (OFF_MUL + 102400)
#define OFF_Q    (OFF_IM  + 204800)
#define OFF_PART (OFF_Q   + 512)
#define OFF_FEAT (OFF_PART + 16777216)
#define OFF_FH   (OFF_FEAT + 2097152)
#define OFF_FL   (OFF_FH   + 1048576)
#define OFF_HB   (OFF_FL   + 1048576)
#define OFF_HH   (OFF_HB   + 2097152)
#define OFF_HL   (OFF_HH   + 1048576)
#define OFF_DZH  (OFF_HL   + 1048576)
#define OFF_DZL  (OFF_DZH  + 1048576)

__device__ __forceinline__ void gbar(unsigned* cnt, unsigned* go, int phase) {
    __syncthreads();
    if (threadIdx.x == 0) {
        __threadfence();
        unsigned prev = __hip_atomic_fetch_add(cnt, 1u, __ATOMIC_ACQ_REL, __HIP_MEMORY_SCOPE_AGENT);
        if (prev == (unsigned)(phase * NBLK - 1)) {
            __hip_atomic_store(go, (unsigned)phase, __ATOMIC_RELEASE, __HIP_MEMORY_SCOPE_AGENT);
        } else {
            while (__hip_atomic_load(go, __ATOMIC_ACQUIRE, __HIP_MEMORY_SCOPE_AGENT) < (unsigned)phase)
                __builtin_amdgcn_s_sleep(4);
        }
        __threadfence();
    }
    __syncthreads();
}

__device__ __forceinline__ void split4g(const float* __restrict__ in, short* __restrict__ oh,
                                        short* __restrict__ ol, long idx) {
    f32x4 v = *(const f32x4*)(in + idx);
    s16x4 h4, l4;
    #pragma unroll
    for (int j = 0; j < 4; ++j) {
        short hi = f2bf(v[j]);
        h4[j] = hi; l4[j] = f2bf(v[j] - bf2f(hi));
    }
    *(s16x4*)(oh + idx) = h4;
    *(s16x4*)(ol + idx) = l4;
}

// 128x64 tile GEMM: C = A[M,K] @ B^T with B as [N,K]; bf16x3. acc per wave: 2x4 f32x4.
__device__ void gemm_tile(SMemG& sg,
                          const short* __restrict__ Ah, const short* __restrict__ Al,
                          const short* __restrict__ Bh, const short* __restrict__ Bl,
                          int M, long K, int m0, int n0, long kbeg, int nkt,
                          f32x4 (&acc)[2][4])
{
    const int tid = threadIdx.x, lane = tid & 63, w = tid >> 6, wm = w * 32;
    const int lrow = lane & 15, kseg = lane >> 4;
    const int srow = tid >> 3, skc = tid & 7;
    const s16x8 ZV = {0, 0, 0, 0, 0, 0, 0, 0};
    s16x8 rA[4][2], rB[2][2];

    auto ldA = [&](int kt) {
        #pragma unroll
        for (int i = 0; i < 4; ++i) {
            int gr = m0 + srow + i * 32;
            long off = (long)gr * K + kbeg + (long)kt * 64 + skc * 8;
            if (gr < M) { rA[i][0] = *(const s16x8*)(Ah + off); rA[i][1] = *(const s16x8*)(Al + off); }
            else        { rA[i][0] = ZV; rA[i][1] = ZV; }
        }
    };
    auto ldB = [&](int kt) {
        #pragma unroll
        for (int i = 0; i < 2; ++i) {
            int gn = n0 + srow + i * 32;
            long off = (long)gn * K + kbeg + (long)kt * 64 + skc * 8;
            rB[i][0] = *(const s16x8*)(Bh + off);
            rB[i][1] = *(const s16x8*)(Bl + off);
        }
    };

    ldA(0); ldB(0);
    for (int kt = 0; kt < nkt; ++kt) {
        #pragma unroll
        for (int i = 0; i < 4; ++i) {
            int r = srow + i * 32;
            *(s16x8*)&sg.As[0][r * PITCH + skc * 8] = rA[i][0];
            *(s16x8*)&sg.As[1][r * PITCH + skc * 8] = rA[i][1];
        }
        #pragma unroll
        for (int i = 0; i < 2; ++i) {
            int r = srow + i * 32;
            *(s16x8*)&sg.Bs[0][r * PITCH + skc * 8] = rB[i][0];
            *(s16x8*)&sg.Bs[1][r * PITCH + skc * 8] = rB[i][1];
        }
        __syncthreads();
        if (kt + 1 < nkt) { ldA(kt + 1); ldB(kt + 1); }
        #pragma unroll
        for (int kk = 0; kk < 2; ++kk) {
            s16x8 ah[2], al[2], bh[4], bl[4];
            #pragma unroll
            for (int i = 0; i < 2; ++i) {
                int rr = (wm + i * 16 + lrow) * PITCH + kk * 32 + kseg * 8;
                ah[i] = *(const s16x8*)&sg.As[0][rr];
                al[i] = *(const s16x8*)&sg.As[1][rr];
            }
            #pragma unroll
            for (int j = 0; j < 4; ++j) {
                int rr = (j * 16 + lrow) * PITCH + kk * 32 + kseg * 8;
                bh[j] = *(const s16x8*)&sg.Bs[0][rr];
                bl[j] = *(const s16x8*)&sg.Bs[1][rr];
            }
            #pragma unroll
            for (int i = 0; i < 2; ++i)
                #pragma unroll
                for (int j = 0; j < 4; ++j) {
                    acc[i][j] = __builtin_amdgcn_mfma_f32_16x16x32_bf16(ah[i], bh[j], acc[i][j], 0, 0, 0);
                    acc[i][j] = __builtin_amdgcn_mfma_f32_16x16x32_bf16(ah[i], bl[j], acc[i][j], 0, 0, 0);
                    acc[i][j] = __builtin_amdgcn_mfma_f32_16x16x32_bf16(al[i], bh[j], acc[i][j], 0, 0, 0);
                }
        }
        __syncthreads();
    }
}

__device__ __forceinline__ void zacc(f32x4 (&acc)[2][4]) {
    #pragma unroll
    for (int i = 0; i < 2; ++i)
        #pragma unroll
        for (int j = 0; j < 4; ++j)
            acc[i][j] = f32x4{0.f, 0.f, 0.f, 0.f};
}

// reduce NZ split-K slabs of [1024x512], optional bias+relu, emit fp32 + hi/lo.
__device__ void reduce_mn(const float* __restrict__ part, int NZ, const float* __restrict__ bias,
                          float* __restrict__ f32o, short* __restrict__ oh, short* __restrict__ ol,
                          int bid)
{
    long i = (long)bid * NTHR + threadIdx.x;      // 131072 total = NBLK*NTHR exactly
    long idx = i * 4;
    f32x4 v = *(const f32x4*)(part + idx);
    for (int z = 1; z < NZ; ++z)
        v += *(const f32x4*)(part + (long)z * 524288 + idx);
    s16x4 h4, l4;
    if (bias) {
        int gn = (int)(idx & 511);
        f32x4 bb = *(const f32x4*)(bias + gn);
        #pragma unroll
        for (int j = 0; j < 4; ++j) v[j] = fmaxf(v[j] + bb[j], 0.f);
    }
    #pragma unroll
    for (int j = 0; j < 4; ++j) {
        short hi = f2bf(v[j]);
        h4[j] = hi; l4[j] = f2bf(v[j] - bf2f(hi));
    }
    *(f32x4*)(f32o + idx) = v;
    *(s16x4*)(oh + idx) = h4;
    *(s16x4*)(ol + idx) = l4;
}

// Fused tail: t = h@mu^T (M=64 rows/block, N=112 padded, K=512).
// passA: argmax(2t - q) -> dz rows.  passB: s = feat.h; out = 2t - s - q.
__device__ void phase_tail(SMemT& st, int bid,
                           const short* __restrict__ h_h, const short* __restrict__ h_l,
                           const short* __restrict__ mu_h, const short* __restrict__ mu_l,
                           const float* __restrict__ feat, const float* __restrict__ hbuf,
                           const float* __restrict__ im, const float* __restrict__ q,
                           short* __restrict__ dz_h, short* __restrict__ dz_l,
                           float* __restrict__ out, bool passB)
{
    const int tid = threadIdx.x, lane = tid & 63, w = tid >> 6;
    const int m0 = bid * 64;
    const int lrow = lane & 15, kseg = lane >> 4;
    const s16x8 ZV = {0, 0, 0, 0, 0, 0, 0, 0};

    if (passB) {
        for (int r = w; r < 64; r += 4) {
            const float* fr = feat + (long)(m0 + r) * 512;
            const float* hr = hbuf + (long)(m0 + r) * 512;
            float ssum = 0.f;
            #pragma unroll
            for (int j = 0; j < 8; ++j) ssum += fr[lane * 8 + j] * hr[lane * 8 + j];
            #pragma unroll
            for (int off = 32; off; off >>= 1) ssum += __shfl_down(ssum, off);
            if (lane == 0) st.srow[r] = ssum;
        }
        __syncthreads();
    }

    f32x4 acc[7];
    #pragma unroll
    for (int j = 0; j < 7; ++j) acc[j] = f32x4{0.f, 0.f, 0.f, 0.f};

    const int sr = tid >> 2, chb = (tid & 3) * 2;
    for (int kt = 0; kt < 8; ++kt) {
        long gk = (long)kt * 64;
        #pragma unroll
        for (int j = 0; j < 2; ++j) {
            int cc = chb + j;
            long src = (long)(m0 + sr) * 512 + gk + cc * 8;
            *(s16x8*)&st.Hs[0][sr * PITCH + cc * 8] = *(const s16x8*)(h_h + src);
            *(s16x8*)&st.Hs[1][sr * PITCH + cc * 8] = *(const s16x8*)(h_l + src);
        }
        for (int rr = sr; rr < 112; rr += 64) {
            #pragma unroll
            for (int j = 0; j < 2; ++j) {
                int cc = chb + j;
                s16x8 vh = ZV, vl = ZV;
                if (rr < 100) {
                    long src = (long)rr * 512 + gk + cc * 8;
                    vh = *(const s16x8*)(mu_h + src);
                    vl = *(const s16x8*)(mu_l + src);
                }
                *(s16x8*)&st.Ms[0][rr * PITCH + cc * 8] = vh;
                *(s16x8*)&st.Ms[1][rr * PITCH + cc * 8] = vl;
            }
        }
        __syncthreads();
        #pragma unroll
        for (int kk = 0; kk < 2; ++kk) {
            int ra = (w * 16 + lrow) * PITCH + kk * 32 + kseg * 8;
            s16x8 ah = *(const s16x8*)&st.Hs[0][ra];
            s16x8 al = *(const s16x8*)&st.Hs[1][ra];
            #pragma unroll
            for (int j = 0; j < 7; ++j) {
                int rb = (j * 16 + lrow) * PITCH + kk * 32 + kseg * 8;
                s16x8 bh = *(const s16x8*)&st.Ms[0][rb];
                s16x8 bl = *(const s16x8*)&st.Ms[1][rb];
                acc[j] = __builtin_amdgcn_mfma_f32_16x16x32_bf16(ah, bh, acc[j], 0, 0, 0);
                acc[j] = __builtin_amdgcn_mfma_f32_16x16x32_bf16(ah, bl, acc[j], 0, 0, 0);
                acc[j] = __builtin_amdgcn_mfma_f32_16x16x32_bf16(al, bh, acc[j], 0, 0, 0);
            }
        }
        __syncthreads();
    }

    const int crow = (lane >> 4) * 4, ccol = lane & 15;
    if (!passB) {
        #pragma unroll
        for (int r = 0; r < 4; ++r) {
            float best = -INFINITY; int bestc = 0;
            #pragma unroll
            for (int j = 0; j < 7; ++j) {
                int n = j * 16 + ccol;
                if (n < 100) {
                    float v = 2.f * acc[j][r] - q[n];
                    if (v > best) { best = v; bestc = n; }
                }
            }
            #pragma unroll
            for (int mk = 1; mk <= 8; mk <<= 1) {
                float ov = __shfl_xor(best, mk);
                int   oc = __shfl_xor(bestc, mk);
                if (ov > best || (ov == best && oc < bestc)) { best = ov; bestc = oc; }
            }
            if (ccol == 0) st.cst[w * 16 + crow + r] = bestc;
        }
        __syncthreads();
        for (int i = tid; i < 64 * 512; i += NTHR) {
            int r = i >> 9, d = i & 511;
            long gi = (long)(m0 + r) * 512 + d;
            float f = feat[gi];
            float v = (f > 0.f) ? -2.f * (hbuf[gi] - im[(long)st.cst[r] * 512 + d]) : 0.f;
            short hi = f2bf(v);
            dz_h[gi] = hi; dz_l[gi] = f2bf(v - bf2f(hi));
        }
    } else {
        #pragma unroll
        for (int j = 0; j < 7; ++j) {
            int n = j * 16 + ccol;
            if (n < 100)
                #pragma unroll
                for (int r = 0; r < 4; ++r) {
                    int rl = w * 16 + crow + r;
                    out[(long)(m0 + rl) * 100 + n] = 2.f * acc[j][r] - st.srow[rl] - q[n];
                }
        }
    }
}

__global__ __launch_bounds__(NTHR, 2) void odin_mega(
    const float* __restrict__ x, const float* __restrict__ W, const float* __restrict__ bias,
    const float* __restrict__ mu, const float* __restrict__ invsig,
    float* __restrict__ out, char* __restrict__ ws)
{
    __shared__ SMem sm;
    unsigned* cnt = (unsigned*)ws;
    unsigned* go  = (unsigned*)(ws + 128);
    short* x_h  = (short*)(ws + OFF_XH);
    short* x_l  = (short*)(ws + OFF_XL);
    short* Wt_h = (short*)(ws + OFF_WTH);
    short* Wt_l = (short*)(ws + OFF_WTL);
    short* W_h  = (short*)(ws + OFF_WH);
    short* W_l  = (short*)(ws + OFF_WL);
    short* is_h = (short*)(ws + OFF_ISH);
    short* is_l = (short*)(ws + OFF_ISL);
    short* mu_h = (short*)(ws + OFF_MUH);
    short* mu_l = (short*)(ws + OFF_MUL);
    float* im   = (float*)(ws + OFF_IM);
    float* q    = (float*)(ws + OFF_Q);
    float* part = (float*)(ws + OFF_PART);
    float* feat = (float*)(ws + OFF_FEAT);
    short* f_h  = (short*)(ws + OFF_FH);
    short* f_l  = (short*)(ws + OFF_FL);
    float* hbuf = (float*)(ws + OFF_HB);
    short* h_h  = (short*)(ws + OFF_HH);
    short* h_l  = (short*)(ws + OFF_HL);
    short* dz_h = (short*)(ws + OFF_DZH);
    short* dz_l = (short*)(ws + OFF_DZL);

    const int bid = blockIdx.x, tid = threadIdx.x;
    const int lane = tid & 63, w = tid >> 6;
    const long gstride = (long)NBLK * NTHR;

    // ---------- P0: split x, invsig, mu; W -> W_h/l and Wt_h/l (tiled transpose) ----------
    for (long i = (long)bid * NTHR + tid; i < (long)Bb * INn / 4; i += gstride)
        split4g(x, x_h, x_l, i * 4);
    for (long i = (long)bid * NTHR + tid; i < (long)Dd * Dd / 4; i += gstride)
        split4g(invsig, is_h, is_l, i * 4);
    for (long i = (long)bid * NTHR + tid; i < (long)Cc * Dd / 4; i += gstride)
        split4g(mu, mu_h, mu_l, i * 4);
    for (int tix = bid; tix < 1536; tix += NBLK) {
        int tr = tix >> 4, tc = tix & 15;
        int r0 = tr * 32, c0 = tc * 32;
        int tx = tid & 31, ty = tid >> 5;
        #pragma unroll
        for (int i2 = 0; i2 < 4; ++i2) {
            int r = r0 + ty + i2 * 8;
            float v = W[(long)r * Dd + c0 + tx];
            sm.r.tp[ty + i2 * 8][tx] = v;
            short hi = f2bf(v);
            W_h[(long)r * Dd + c0 + tx] = hi;
            W_l[(long)r * Dd + c0 + tx] = f2bf(v - bf2f(hi));
        }
        __syncthreads();
        #pragma unroll
        for (int i2 = 0; i2 < 4; ++i2) {
            int c = c0 + ty + i2 * 8;
            float v = sm.r.tp[tx][ty + i2 * 8];
            short hi = f2bf(v);
            Wt_h[(long)c * INn + r0 + tx] = hi;
            Wt_l[(long)c * INn + r0 + tx] = f2bf(v - bf2f(hi));
        }
        __syncthreads();
    }
    gbar(cnt, go, 1);

    // ---------- P1: im = mu@invsig (blocks 0..7) || x@W split-K6 partials (8..391) ----------
    if (bid < 8) {
        f32x4 acc[2][4]; zacc(acc);
        gemm_tile(sm.g, mu_h, mu_l, is_h, is_l, Cc, Dd, 0, bid * 64, 0, 8, acc);
        const int crow = (lane >> 4) * 4, ccol = lane & 15, wm = w * 32;
        #pragma unroll
        for (int i = 0; i < 2; ++i)
            #pragma unroll
            for (int j = 0; j < 4; ++j)
                #pragma unroll
                for (int r = 0; r < 4; ++r) {
                    int gm = wm + i * 16 + crow + r, gn = bid * 64 + j * 16 + ccol;
                    if (gm < Cc) im[(long)gm * Dd + gn] = acc[i][j][r];
                }
    } else if (bid < 392) {
        int idx = bid - 8, z = idx >> 6, rem = idx & 63, tm = rem >> 3, tn = rem & 7;
        f32x4 acc[2][4]; zacc(acc);
        gemm_tile(sm.g, x_h, x_l, Wt_h, Wt_l, Bb, INn, tm * 128, tn * 64, (long)z * 512, 8, acc);
        const int crow = (lane >> 4) * 4, ccol = lane & 15, wm = w * 32;
        float* dst = part + (long)z * 524288;
        #pragma unroll
        for (int i = 0; i < 2; ++i)
            #pragma unroll
            for (int j = 0; j < 4; ++j)
                #pragma unroll
                for (int r = 0; r < 4; ++r)
                    dst[(long)(tm * 128 + wm + i * 16 + crow + r) * Dd + tn * 64 + j * 16 + ccol] = acc[i][j][r];
    }
    gbar(cnt, go, 2);

    // ---------- P2: reduce+bias+relu -> feat ; q[c] on blocks <100 ----------
    reduce_mn(part, 6, bias, feat, f_h, f_l, bid);
    if (bid < 100) {
        float sum = 0.f;
        for (int d = tid; d < 512; d += NTHR) sum += mu[(long)bid * 512 + d] * im[(long)bid * 512 + d];
        #pragma unroll
        for (int off = 32; off; off >>= 1) sum += __shfl_down(sum, off);
        if (lane == 0) sm.r.red[w] = sum;
        __syncthreads();
        if (tid == 0) q[bid] = sm.r.red[0] + sm.r.red[1] + sm.r.red[2] + sm.r.red[3];
    }
    gbar(cnt, go, 3);

    // ---------- P3: h partials split-K8 (512 blocks) ----------
    {
        int z = bid >> 6, rem = bid & 63, tm = rem >> 3, tn = rem & 7;
        f32x4 acc[2][4]; zacc(acc);
        gemm_tile(sm.g, f_h, f_l, is_h, is_l, Bb, Dd, tm * 128, tn * 64, (long)z * 64, 1, acc);
        const int crow = (lane >> 4) * 4, ccol = lane & 15, wm = w * 32;
        float* dst = part + (long)z * 524288;
        #pragma unroll
        for (int i = 0; i < 2; ++i)
            #pragma unroll
            for (int j = 0; j < 4; ++j)
                #pragma unroll
                for (int r = 0; r < 4; ++r)
                    dst[(long)(tm * 128 + wm + i * 16 + crow + r) * Dd + tn * 64 + j * 16 + ccol] = acc[i][j][r];
    }
    gbar(cnt, go, 4);

    // ---------- P4: reduce -> hbuf ----------
    reduce_mn(part, 8, nullptr, hbuf, h_h, h_l, bid);
    gbar(cnt, go, 5);

    // ---------- P5: t + argmax + dz (blocks 0..15) ----------
    if (bid < 16)
        phase_tail(sm.t, bid, h_h, h_l, mu_h, mu_l, feat, hbuf, im, q, dz_h, dz_l, out, false);
    gbar(cnt, go, 6);

    // ---------- P6: xadv = clip(x + eps * dz@W^T) -> x_h/x_l ----------
    if (bid < 384) {
        int tm = bid / 48, tn = bid % 48;
        f32x4 acc[2][4]; zacc(acc);
        gemm_tile(sm.g, dz_h, dz_l, W_h, W_l, Bb, Dd, tm * 128, tn * 64, 0, 8, acc);
        const int crow = (lane >> 4) * 4, ccol = lane & 15, wm = w * 32;
        #pragma unroll
        for (int i = 0; i < 2; ++i)
            #pragma unroll
            for (int j = 0; j < 4; ++j)
                #pragma unroll
                for (int r = 0; r < 4; ++r) {
                    long cidx = (long)(tm * 128 + wm + i * 16 + crow + r) * INn + tn * 64 + j * 16 + ccol;
                    float v = x[cidx] + EPS_ODIN * acc[i][j][r];
                    v = fminf(fmaxf(v, 0.f), 1.f);
                    short hi = f2bf(v);
                    x_h[cidx] = hi; x_l[cidx] = f2bf(v - bf2f(hi));
                }
    }
    gbar(cnt, go, 7);

    // ---------- P7: feat2 partials ----------
    if (bid < 384) {
        int z = bid >> 6, rem = bid & 63, tm = rem >> 3, tn = rem & 7;
        f32x4 acc[2][4]; zacc(acc);
        gemm_tile(sm.g, x_h, x_l, Wt_h, Wt_l, Bb, INn, tm * 128, tn * 64, (long)z * 512, 8, acc);
        const int crow = (lane >> 4) * 4, ccol = lane & 15, wm = w * 32;
        float* dst = part + (long)z * 524288;
        #pragma unroll
        for (int i = 0; i < 2; ++i)
            #pragma unroll
            for (int j = 0; j < 4; ++j)
                #pragma unroll
                for (int r = 0; r < 4; ++r)
                    dst[(long)(tm * 128 + wm + i * 16 + crow + r) * Dd + tn * 64 + j * 16 + ccol] = acc[i][j][r];
    }
    gbar(cnt, go, 8);

    // ---------- P8: reduce+bias+relu -> feat2 ----------
    reduce_mn(part, 6, bias, feat, f_h, f_l, bid);
    gbar(cnt, go, 9);

    // ---------- P9: h2 partials ----------
    {
        int z = bid >> 6, rem = bid & 63, tm = rem >> 3, tn = rem & 7;
        f32x4 acc[2][4]; zacc(acc);
        gemm_tile(sm.g, f_h, f_l, is_h, is_l, Bb, Dd, tm * 128, tn * 64, (long)z * 64, 1, acc);
        const int crow = (lane >> 4) * 4, ccol = lane & 15, wm = w * 32;
        float* dst = part + (long)z * 524288;
        #pragma unroll
        for (int i = 0; i < 2; ++i)
            #pragma unroll
            for (int j = 0; j < 4; ++j)
                #pragma unroll
                for (int r = 0; r < 4; ++r)
                    dst[(long)(tm * 128 + wm + i * 16 + crow + r) * Dd + tn * 64 + j * 16 + ccol] = acc[i][j][r];
    }
    gbar(cnt, go, 10);

    // ---------- P10: reduce -> h2 ----------
    reduce_mn(part, 8, nullptr, hbuf, h_h, h_l, bid);
    gbar(cnt, go, 11);

    // ---------- P11: s + out (blocks 0..15) ----------
    if (bid < 16)
        phase_tail(sm.t, bid, h_h, h_l, mu_h, mu_l, feat, hbuf, im, q, dz_h, dz_l, out, true);
}

extern "C" void kernel_launch(void* const* d_in, const int* in_sizes, int n_in,
                              void* d_out, int out_size, void* d_ws, size_t ws_size,
                              hipStream_t stream)
{
    const float* x      = (const float*)d_in[0];
    const float* W      = (const float*)d_in[1];
    const float* bias   = (const float*)d_in[2];
    const float* mu     = (const float*)d_in[3];
    const float* invsig = (const float*)d_in[4];
    float* out = (float*)d_out;

    hipMemsetAsync(d_ws, 0, 256, stream);
    odin_mega<<<NBLK, NTHR, 0, stream>>>(x, W, bias, mu, invsig, out, (char*)d_ws);
}

// Round 5
// 211.386 us; speedup vs baseline: 6.0818x; 6.0818x over previous
//
#include <hip/hip_runtime.h>
#include <hip/hip_bf16.h>

#define EPS_ODIN 0.0014f

constexpr int Bb  = 1024;
constexpr int Cc  = 100;
constexpr int Dd  = 512;
constexpr int INn = 3072;
constexpr int PITCH = 68;   // shorts; 136B pitch

using s16x8 = __attribute__((ext_vector_type(8))) short;
using s16x4 = __attribute__((ext_vector_type(4))) short;
using f32x4 = __attribute__((ext_vector_type(4))) float;

__device__ __forceinline__ short f2bf(float f) {
    __hip_bfloat16 h = __float2bfloat16(f);
    return *reinterpret_cast<short*>(&h);
}

// ---------------- prep: fp32 -> bf16 planes + W transpose ----------------
__global__ __launch_bounds__(256) void prep_kernel(
    const float* __restrict__ x, const float* __restrict__ W,
    const float* __restrict__ invsig, const float* __restrict__ mu,
    short* __restrict__ x_b, short* __restrict__ W_b, short* __restrict__ Wt_b,
    short* __restrict__ is_b, short* __restrict__ mu_b)
{
    __shared__ float tp[32][33];
    const int tid = threadIdx.x, bid = blockIdx.x;
    const long gstride = (long)gridDim.x * 256;
    auto cvt4 = [&](const float* in, short* ob, long q) {
        long idx = q * 4;
        f32x4 v = *(const f32x4*)(in + idx);
        s16x4 o;
        #pragma unroll
        for (int j = 0; j < 4; ++j) o[j] = f2bf(v[j]);
        *(s16x4*)(ob + idx) = o;
    };
    for (long i = (long)bid * 256 + tid; i < (long)Bb * INn / 4; i += gstride) cvt4(x, x_b, i);
    for (long i = (long)bid * 256 + tid; i < (long)Dd * Dd / 4; i += gstride) cvt4(invsig, is_b, i);
    for (long i = (long)bid * 256 + tid; i < (long)Cc * Dd / 4; i += gstride) cvt4(mu, mu_b, i);

    const int tx = tid & 31, ty = tid >> 5;
    for (int tix = bid; tix < (INn / 32) * (Dd / 32); tix += gridDim.x) {
        int r0 = (tix >> 4) * 32, c0 = (tix & 15) * 32;
        #pragma unroll
        for (int i2 = 0; i2 < 4; ++i2) {
            int r = r0 + ty + i2 * 8;
            float v = W[(long)r * Dd + c0 + tx];
            tp[ty + i2 * 8][tx] = v;
            W_b[(long)r * Dd + c0 + tx] = f2bf(v);
        }
        __syncthreads();
        #pragma unroll
        for (int i2 = 0; i2 < 4; ++i2) {
            int c = c0 + ty + i2 * 8;
            Wt_b[(long)c * INn + r0 + tx] = f2bf(tp[tx][ty + i2 * 8]);
        }
        __syncthreads();
    }
}

// ---------------- im = mu @ invsig (fp32 exact) ; q[c] = mu_c . im_c ----------------
__global__ __launch_bounds__(256) void im_q_kernel(
    const float* __restrict__ mu, const float* __restrict__ invsig,
    float* __restrict__ im, float* __restrict__ q)
{
    __shared__ float muc[512];
    __shared__ float red[4];
    const int tid = threadIdx.x, c = blockIdx.x;
    for (int e = tid; e < 512; e += 256) muc[e] = mu[(long)c * 512 + e];
    __syncthreads();
    const int d0 = tid, d1 = tid + 256;
    float a0 = 0.f, a1 = 0.f, a2 = 0.f, a3 = 0.f;
    for (int e = 0; e < 512; e += 2) {
        float m0 = muc[e], m1 = muc[e + 1];
        a0 = fmaf(m0, invsig[(long)e * 512 + d0], a0);
        a1 = fmaf(m0, invsig[(long)e * 512 + d1], a1);
        a2 = fmaf(m1, invsig[(long)(e + 1) * 512 + d0], a2);
        a3 = fmaf(m1, invsig[(long)(e + 1) * 512 + d1], a3);
    }
    float r0 = a0 + a2, r1 = a1 + a3;
    im[(long)c * 512 + d0] = r0;
    im[(long)c * 512 + d1] = r1;
    float s = muc[d0] * r0 + muc[d1] * r1;
    #pragma unroll
    for (int off = 32; off; off >>= 1) s += __shfl_down(s, off);
    if ((tid & 63) == 0) red[tid >> 6] = s;
    __syncthreads();
    if (tid == 0) q[c] = red[0] + red[1] + red[2] + red[3];
}

// ---------------- single-plane bf16 GEMM, 128x64 tile, BK=64 ----------------
// C = A[M,K] @ B^T, B given [N,K]. EPI: 0 -> part slab (z), 1 -> fp32 + bf16, 2 -> xadv bf16
template<int EPI>
__global__ __launch_bounds__(256, 4) void gemm_b1(
    const short* __restrict__ A, const short* __restrict__ Bm,
    float* __restrict__ Cm, long K, int kcount, int N,
    const float* __restrict__ aux1, short* __restrict__ obf, float esc)
{
    __shared__ short As[128 * PITCH];
    __shared__ short Bs[64 * PITCH];
    const int tid = threadIdx.x;
    const int m0 = blockIdx.y * 128, n0 = blockIdx.x * 64;
    const long kbeg = (long)blockIdx.z * kcount;
    const int lane = tid & 63, w = tid >> 6, wm = w * 32;
    const int lrow = lane & 15, kseg = lane >> 4;
    const int srow = tid >> 3, skc = (tid & 7) * 8;
    const int nkt = kcount >> 6;

    f32x4 acc[2][4];
    #pragma unroll
    for (int i = 0; i < 2; ++i)
        #pragma unroll
        for (int j = 0; j < 4; ++j)
            acc[i][j] = f32x4{0.f, 0.f, 0.f, 0.f};

    s16x8 rA[4], rB[2];
    auto ldA = [&](int kt) {
        #pragma unroll
        for (int i = 0; i < 4; ++i)
            rA[i] = *(const s16x8*)(A + (long)(m0 + srow + i * 32) * K + kbeg + (long)kt * 64 + skc);
    };
    auto ldB = [&](int kt) {
        #pragma unroll
        for (int i = 0; i < 2; ++i)
            rB[i] = *(const s16x8*)(Bm + (long)(n0 + srow + i * 32) * K + kbeg + (long)kt * 64 + skc);
    };

    ldA(0); ldB(0);
    for (int kt = 0; kt < nkt; ++kt) {
        #pragma unroll
        for (int i = 0; i < 4; ++i)
            *(s16x8*)&As[(srow + i * 32) * PITCH + skc] = rA[i];
        #pragma unroll
        for (int i = 0; i < 2; ++i)
            *(s16x8*)&Bs[(srow + i * 32) * PITCH + skc] = rB[i];
        __syncthreads();
        if (kt + 1 < nkt) { ldA(kt + 1); ldB(kt + 1); }
        #pragma unroll
        for (int kk = 0; kk < 2; ++kk) {
            s16x8 ah[2], bfr[4];
            #pragma unroll
            for (int i = 0; i < 2; ++i)
                ah[i] = *(const s16x8*)&As[(wm + i * 16 + lrow) * PITCH + kk * 32 + kseg * 8];
            #pragma unroll
            for (int j = 0; j < 4; ++j)
                bfr[j] = *(const s16x8*)&Bs[(j * 16 + lrow) * PITCH + kk * 32 + kseg * 8];
            #pragma unroll
            for (int i = 0; i < 2; ++i)
                #pragma unroll
                for (int j = 0; j < 4; ++j)
                    acc[i][j] = __builtin_amdgcn_mfma_f32_16x16x32_bf16(ah[i], bfr[j], acc[i][j], 0, 0, 0);
        }
        __syncthreads();
    }

    const int crow = (lane >> 4) * 4, ccol = lane & 15;
    #pragma unroll
    for (int i = 0; i < 2; ++i)
        #pragma unroll
        for (int j = 0; j < 4; ++j)
            #pragma unroll
            for (int r = 0; r < 4; ++r) {
                int gm = m0 + wm + i * 16 + crow + r;
                int gn = n0 + j * 16 + ccol;
                float v = acc[i][j][r];
                if (EPI == 0) {
                    (Cm + (long)blockIdx.z * Bb * Dd)[(long)gm * 512 + gn] = v;
                } else if (EPI == 1) {
                    long cidx = (long)gm * N + gn;
                    Cm[cidx] = v;
                    obf[cidx] = f2bf(v);
                } else {
                    long cidx = (long)gm * N + gn;
                    float u = aux1[cidx] + esc * v;
                    u = fminf(fmaxf(u, 0.f), 1.f);
                    obf[cidx] = f2bf(u);
                }
            }
}

// ---------------- reduce 8 split-K slabs + bias + relu -> feat fp32 + bf16 ----------------
__global__ __launch_bounds__(256) void reduce_feat(
    const float* __restrict__ part, const float* __restrict__ bias,
    float* __restrict__ feat, short* __restrict__ fb)
{
    long idx = ((long)blockIdx.x * 256 + threadIdx.x) * 4;
    f32x4 v = *(const f32x4*)(part + idx);
    #pragma unroll
    for (int z = 1; z < 8; ++z)
        v += *(const f32x4*)(part + (long)z * Bb * Dd + idx);
    f32x4 bb = *(const f32x4*)(bias + (idx & 511));
    s16x4 o;
    #pragma unroll
    for (int j = 0; j < 4; ++j) {
        v[j] = fmaxf(v[j] + bb[j], 0.f);
        o[j] = f2bf(v[j]);
    }
    *(f32x4*)(feat + idx) = v;
    *(s16x4*)(fb + idx) = o;
}

// ---------------- fused tail: t = h@mu^T (64 rows/block, N=112 pad) ----------------
// PASSB=false: argmax(2t-q) -> dz bf16.  PASSB=true: s = feat.h ; out = 2t - s - q.
template<bool PASSB>
__global__ __launch_bounds__(256) void tail_kernel(
    const short* __restrict__ h_b, const short* __restrict__ mu_b,
    const float* __restrict__ feat, const float* __restrict__ hbuf,
    const float* __restrict__ im, const float* __restrict__ q,
    short* __restrict__ dz_b, float* __restrict__ out)
{
    __shared__ short Hs[64 * PITCH];
    __shared__ short Ms[112 * PITCH];
    __shared__ float srow[64];
    __shared__ int   cstv[64];
    const int tid = threadIdx.x, lane = tid & 63, w = tid >> 6;
    const int m0 = blockIdx.x * 64;
    const int lrow = lane & 15, kseg = lane >> 4;
    const s16x8 ZV = {0, 0, 0, 0, 0, 0, 0, 0};

    if (PASSB) {
        for (int r = w; r < 64; r += 4) {
            const float* fr = feat + (long)(m0 + r) * 512;
            const float* hr = hbuf + (long)(m0 + r) * 512;
            float ssum = 0.f;
            #pragma unroll
            for (int j = 0; j < 8; ++j) ssum += fr[lane * 8 + j] * hr[lane * 8 + j];
            #pragma unroll
            for (int off = 32; off; off >>= 1) ssum += __shfl_down(ssum, off);
            if (lane == 0) srow[r] = ssum;
        }
        __syncthreads();
    }

    f32x4 acc[7];
    #pragma unroll
    for (int j = 0; j < 7; ++j) acc[j] = f32x4{0.f, 0.f, 0.f, 0.f};

    const int sr = tid >> 2, chb = (tid & 3) * 2;
    for (int kt = 0; kt < 8; ++kt) {
        long gk = (long)kt * 64;
        #pragma unroll
        for (int j = 0; j < 2; ++j) {
            int cc = chb + j;
            *(s16x8*)&Hs[sr * PITCH + cc * 8] = *(const s16x8*)(h_b + (long)(m0 + sr) * 512 + gk + cc * 8);
        }
        for (int rr = sr; rr < 112; rr += 64) {
            #pragma unroll
            for (int j = 0; j < 2; ++j) {
                int cc = chb + j;
                s16x8 vh = ZV;
                if (rr < 100) vh = *(const s16x8*)(mu_b + (long)rr * 512 + gk + cc * 8);
                *(s16x8*)&Ms[rr * PITCH + cc * 8] = vh;
            }
        }
        __syncthreads();
        #pragma unroll
        for (int kk = 0; kk < 2; ++kk) {
            s16x8 ah = *(const s16x8*)&Hs[(w * 16 + lrow) * PITCH + kk * 32 + kseg * 8];
            #pragma unroll
            for (int j = 0; j < 7; ++j) {
                s16x8 bh = *(const s16x8*)&Ms[(j * 16 + lrow) * PITCH + kk * 32 + kseg * 8];
                acc[j] = __builtin_amdgcn_mfma_f32_16x16x32_bf16(ah, bh, acc[j], 0, 0, 0);
            }
        }
        __syncthreads();
    }

    const int crow = (lane >> 4) * 4, ccol = lane & 15;
    if (!PASSB) {
        #pragma unroll
        for (int r = 0; r < 4; ++r) {
            float best = -INFINITY; int bestc = 0;
            #pragma unroll
            for (int j = 0; j < 7; ++j) {
                int n = j * 16 + ccol;
                if (n < 100) {
                    float v = 2.f * acc[j][r] - q[n];
                    if (v > best) { best = v; bestc = n; }
                }
            }
            #pragma unroll
            for (int mk = 1; mk <= 8; mk <<= 1) {
                float ov = __shfl_xor(best, mk);
                int   oc = __shfl_xor(bestc, mk);
                if (ov > best || (ov == best && oc < bestc)) { best = ov; bestc = oc; }
            }
            if (ccol == 0) cstv[w * 16 + crow + r] = bestc;
        }
        __syncthreads();
        for (int i = tid; i < 64 * 512; i += 256) {
            int r = i >> 9, d = i & 511;
            long gi = (long)(m0 + r) * 512 + d;
            float f = feat[gi];
            float v = (f > 0.f) ? -2.f * (hbuf[gi] - im[(long)cstv[r] * 512 + d]) : 0.f;
            dz_b[gi] = f2bf(v);
        }
    } else {
        #pragma unroll
        for (int j = 0; j < 7; ++j) {
            int n = j * 16 + ccol;
            if (n < 100)
                #pragma unroll
                for (int r = 0; r < 4; ++r) {
                    int rl = w * 16 + crow + r;
                    out[(long)(m0 + rl) * 100 + n] = 2.f * acc[j][r] - srow[rl] - q[n];
                }
        }
    }
}

extern "C" void kernel_launch(void* const* d_in, const int* in_sizes, int n_in,
                              void* d_out, int out_size, void* d_ws, size_t ws_size,
                              hipStream_t stream)
{
    const float* x      = (const float*)d_in[0];
    const float* W      = (const float*)d_in[1];
    const float* bias   = (const float*)d_in[2];
    const float* mu     = (const float*)d_in[3];
    const float* invsig = (const float*)d_in[4];
    float* out = (float*)d_out;

    char* wp = (char*)d_ws;
    auto alloc = [&](size_t bytes) { char* p = wp; wp += (bytes + 255) & ~size_t(255); return p; };
    short* x_b  = (short*)alloc((size_t)Bb * INn * 2);   // reused as xadv bf16
    short* Wt_b = (short*)alloc((size_t)Dd * INn * 2);
    short* W_b  = (short*)alloc((size_t)INn * Dd * 2);
    short* is_b = (short*)alloc((size_t)Dd * Dd * 2);
    short* mu_b = (short*)alloc((size_t)Cc * Dd * 2);
    float* im   = (float*)alloc((size_t)Cc * Dd * 4);
    float* q    = (float*)alloc(512);
    float* part = (float*)alloc((size_t)8 * Bb * Dd * 4);
    float* feat = (float*)alloc((size_t)Bb * Dd * 4);
    short* f_b  = (short*)alloc((size_t)Bb * Dd * 2);
    float* hbuf = (float*)alloc((size_t)Bb * Dd * 4);
    short* h_b  = (short*)alloc((size_t)Bb * Dd * 2);
    short* dz_b = (short*)alloc((size_t)Bb * Dd * 2);

    dim3 blk(256);

    // 1. bf16 planes + W transpose
    prep_kernel<<<512, blk, 0, stream>>>(x, W, invsig, mu, x_b, W_b, Wt_b, is_b, mu_b);
    // 2. im (fp32 exact) + q
    im_q_kernel<<<Cc, blk, 0, stream>>>(mu, invsig, im, q);
    // 3. feat partials: x@W split-K8 (512 blocks)
    gemm_b1<0><<<dim3(Dd / 64, Bb / 128, 8), blk, 0, stream>>>(
        x_b, Wt_b, part, INn, INn / 8, Dd, nullptr, nullptr, 0.f);
    // 4. reduce + bias + relu
    reduce_feat<<<512, blk, 0, stream>>>(part, bias, feat, f_b);
    // 5. h = feat @ invsig (direct)
    gemm_b1<1><<<dim3(Dd / 64, Bb / 128, 1), blk, 0, stream>>>(
        f_b, is_b, hbuf, Dd, Dd, Dd, nullptr, h_b, 0.f);
    // 6. t + argmax + dz
    tail_kernel<false><<<Bb / 64, blk, 0, stream>>>(h_b, mu_b, feat, hbuf, im, q, dz_b, out);
    // 7. xadv = clip(x + eps * dz@W^T) -> x_b
    gemm_b1<2><<<dim3(INn / 64, Bb / 128, 1), blk, 0, stream>>>(
        dz_b, W_b, nullptr, Dd, Dd, INn, x, x_b, EPS_ODIN);
    // 8. feat2 partials
    gemm_b1<0><<<dim3(Dd / 64, Bb / 128, 8), blk, 0, stream>>>(
        x_b, Wt_b, part, INn, INn / 8, Dd, nullptr, nullptr, 0.f);
    // 9. reduce
    reduce_feat<<<512, blk, 0, stream>>>(part, bias, feat, f_b);
    // 10. h2
    gemm_b1<1><<<dim3(Dd / 64, Bb / 128, 1), blk, 0, stream>>>(
        f_b, is_b, hbuf, Dd, Dd, Dd, nullptr, h_b, 0.f);
    // 11. s + out
    tail_kernel<true><<<Bb / 64, blk, 0, stream>>>(h_b, mu_b, feat, hbuf, im, q, dz_b, out);
}

// Round 6
// 114.935 us; speedup vs baseline: 11.1856x; 1.8392x over previous
//
#include <hip/hip_runtime.h>
#include <hip/hip_bf16.h>

#define EPS_ODIN 0.0014f

constexpr int Bb  = 1024;
constexpr int Cc  = 100;
constexpr int Dd  = 512;
constexpr int INn = 3072;
constexpr int PITCH = 68;   // shorts; 136B pitch

using s16x8 = __attribute__((ext_vector_type(8))) short;
using s16x4 = __attribute__((ext_vector_type(4))) short;
using f32x4 = __attribute__((ext_vector_type(4))) float;

__device__ __forceinline__ short f2bf(float f) {
    __hip_bfloat16 h = __float2bfloat16(f);
    return *reinterpret_cast<short*>(&h);
}

// ---------------- prep: fp32 -> bf16 planes + W transpose; mu padded to 112 rows ----------------
__global__ __launch_bounds__(256) void prep_kernel(
    const float* __restrict__ x, const float* __restrict__ W,
    const float* __restrict__ invsig, const float* __restrict__ mu,
    short* __restrict__ x_b, short* __restrict__ W_b, short* __restrict__ Wt_b,
    short* __restrict__ is_b, short* __restrict__ mu_b)
{
    __shared__ float tp[32][33];
    const int tid = threadIdx.x, bid = blockIdx.x;
    const long gstride = (long)gridDim.x * 256;
    auto cvt4 = [&](const float* in, short* ob, long q) {
        long idx = q * 4;
        f32x4 v = *(const f32x4*)(in + idx);
        s16x4 o;
        #pragma unroll
        for (int j = 0; j < 4; ++j) o[j] = f2bf(v[j]);
        *(s16x4*)(ob + idx) = o;
    };
    for (long i = (long)bid * 256 + tid; i < (long)Bb * INn / 4; i += gstride) cvt4(x, x_b, i);
    for (long i = (long)bid * 256 + tid; i < (long)Dd * Dd / 4; i += gstride) cvt4(invsig, is_b, i);
    for (long i = (long)bid * 256 + tid; i < (long)112 * Dd / 4; i += gstride) {
        long idx = i * 4;
        if ((idx >> 9) < Cc) cvt4(mu, mu_b, i);
        else *(s16x4*)(mu_b + idx) = s16x4{0, 0, 0, 0};
    }

    const int tx = tid & 31, ty = tid >> 5;
    for (int tix = bid; tix < (INn / 32) * (Dd / 32); tix += gridDim.x) {
        int r0 = (tix >> 4) * 32, c0 = (tix & 15) * 32;
        #pragma unroll
        for (int i2 = 0; i2 < 4; ++i2) {
            int r = r0 + ty + i2 * 8;
            float v = W[(long)r * Dd + c0 + tx];
            tp[ty + i2 * 8][tx] = v;
            W_b[(long)r * Dd + c0 + tx] = f2bf(v);
        }
        __syncthreads();
        #pragma unroll
        for (int i2 = 0; i2 < 4; ++i2) {
            int c = c0 + ty + i2 * 8;
            Wt_b[(long)c * INn + r0 + tx] = f2bf(tp[tx][ty + i2 * 8]);
        }
        __syncthreads();
    }
}

// ---------------- im = mu @ invsig (fp32 exact) ; q[c] = mu_c . im_c ----------------
__global__ __launch_bounds__(256) void im_q_kernel(
    const float* __restrict__ mu, const float* __restrict__ invsig,
    float* __restrict__ im, float* __restrict__ q)
{
    __shared__ float muc[512];
    __shared__ float red[4];
    const int tid = threadIdx.x, c = blockIdx.x;
    for (int e = tid; e < 512; e += 256) muc[e] = mu[(long)c * 512 + e];
    __syncthreads();
    const int d0 = tid, d1 = tid + 256;
    float a0 = 0.f, a1 = 0.f, a2 = 0.f, a3 = 0.f;
    for (int e = 0; e < 512; e += 2) {
        float m0 = muc[e], m1 = muc[e + 1];
        a0 = fmaf(m0, invsig[(long)e * 512 + d0], a0);
        a1 = fmaf(m0, invsig[(long)e * 512 + d1], a1);
        a2 = fmaf(m1, invsig[(long)(e + 1) * 512 + d0], a2);
        a3 = fmaf(m1, invsig[(long)(e + 1) * 512 + d1], a3);
    }
    float r0 = a0 + a2, r1 = a1 + a3;
    im[(long)c * 512 + d0] = r0;
    im[(long)c * 512 + d1] = r1;
    float s = muc[d0] * r0 + muc[d1] * r1;
    #pragma unroll
    for (int off = 32; off; off >>= 1) s += __shfl_down(s, off);
    if ((tid & 63) == 0) red[tid >> 6] = s;
    __syncthreads();
    if (tid == 0) q[c] = red[0] + red[1] + red[2] + red[3];
}

// ---------------- single-plane bf16 GEMM, 128x64 tile, BK=64 ----------------
// C = A[M,K] @ B^T, B given [N,K]. EPI: 0 -> part slab (z), 1 -> fp32 + bf16, 2 -> xadv bf16
template<int EPI>
__global__ __launch_bounds__(256, 4) void gemm_b1(
    const short* __restrict__ A, const short* __restrict__ Bm,
    float* __restrict__ Cm, long K, int kcount, int N,
    const float* __restrict__ aux1, short* __restrict__ obf, float esc)
{
    __shared__ short As[128 * PITCH];
    __shared__ short Bs[64 * PITCH];
    const int tid = threadIdx.x;
    const int m0 = blockIdx.y * 128, n0 = blockIdx.x * 64;
    const long kbeg = (long)blockIdx.z * kcount;
    const int lane = tid & 63, w = tid >> 6, wm = w * 32;
    const int lrow = lane & 15, kseg = lane >> 4;
    const int srow = tid >> 3, skc = (tid & 7) * 8;
    const int nkt = kcount >> 6;

    f32x4 acc[2][4];
    #pragma unroll
    for (int i = 0; i < 2; ++i)
        #pragma unroll
        for (int j = 0; j < 4; ++j)
            acc[i][j] = f32x4{0.f, 0.f, 0.f, 0.f};

    s16x8 rA[4], rB[2];
    auto ldA = [&](int kt) {
        #pragma unroll
        for (int i = 0; i < 4; ++i)
            rA[i] = *(const s16x8*)(A + (long)(m0 + srow + i * 32) * K + kbeg + (long)kt * 64 + skc);
    };
    auto ldB = [&](int kt) {
        #pragma unroll
        for (int i = 0; i < 2; ++i)
            rB[i] = *(const s16x8*)(Bm + (long)(n0 + srow + i * 32) * K + kbeg + (long)kt * 64 + skc);
    };

    ldA(0); ldB(0);
    for (int kt = 0; kt < nkt; ++kt) {
        #pragma unroll
        for (int i = 0; i < 4; ++i)
            *(s16x8*)&As[(srow + i * 32) * PITCH + skc] = rA[i];
        #pragma unroll
        for (int i = 0; i < 2; ++i)
            *(s16x8*)&Bs[(srow + i * 32) * PITCH + skc] = rB[i];
        __syncthreads();
        if (kt + 1 < nkt) { ldA(kt + 1); ldB(kt + 1); }
        #pragma unroll
        for (int kk = 0; kk < 2; ++kk) {
            s16x8 ah[2], bfr[4];
            #pragma unroll
            for (int i = 0; i < 2; ++i)
                ah[i] = *(const s16x8*)&As[(wm + i * 16 + lrow) * PITCH + kk * 32 + kseg * 8];
            #pragma unroll
            for (int j = 0; j < 4; ++j)
                bfr[j] = *(const s16x8*)&Bs[(j * 16 + lrow) * PITCH + kk * 32 + kseg * 8];
            #pragma unroll
            for (int i = 0; i < 2; ++i)
                #pragma unroll
                for (int j = 0; j < 4; ++j)
                    acc[i][j] = __builtin_amdgcn_mfma_f32_16x16x32_bf16(ah[i], bfr[j], acc[i][j], 0, 0, 0);
        }
        __syncthreads();
    }

    const int crow = (lane >> 4) * 4, ccol = lane & 15;
    #pragma unroll
    for (int i = 0; i < 2; ++i)
        #pragma unroll
        for (int j = 0; j < 4; ++j)
            #pragma unroll
            for (int r = 0; r < 4; ++r) {
                int gm = m0 + wm + i * 16 + crow + r;
                int gn = n0 + j * 16 + ccol;
                float v = acc[i][j][r];
                if (EPI == 0) {
                    (Cm + (long)blockIdx.z * Bb * Dd)[(long)gm * 512 + gn] = v;
                } else if (EPI == 1) {
                    long cidx = (long)gm * N + gn;
                    Cm[cidx] = v;
                    obf[cidx] = f2bf(v);
                } else {
                    long cidx = (long)gm * N + gn;
                    float u = aux1[cidx] + esc * v;
                    u = fminf(fmaxf(u, 0.f), 1.f);
                    obf[cidx] = f2bf(u);
                }
            }
}

// ---------------- reduce 8 split-K slabs + bias + relu -> feat fp32 + bf16 ----------------
__global__ __launch_bounds__(256) void reduce_feat(
    const float* __restrict__ part, const float* __restrict__ bias,
    float* __restrict__ feat, short* __restrict__ fb)
{
    long idx = ((long)blockIdx.x * 256 + threadIdx.x) * 4;
    f32x4 v = *(const f32x4*)(part + idx);
    #pragma unroll
    for (int z = 1; z < 8; ++z)
        v += *(const f32x4*)(part + (long)z * Bb * Dd + idx);
    f32x4 bb = *(const f32x4*)(bias + (idx & 511));
    s16x4 o;
    #pragma unroll
    for (int j = 0; j < 4; ++j) {
        v[j] = fmaxf(v[j] + bb[j], 0.f);
        o[j] = f2bf(v[j]);
    }
    *(f32x4*)(feat + idx) = v;
    *(s16x4*)(fb + idx) = o;
}

// ---------------- tail A: t = h@mu^T (16 rows/block, 64 blocks, K split over 4 waves),
//                  argmax(2t-q) -> dz bf16. Register-direct MFMA, no LDS staging. ----------------
__global__ __launch_bounds__(256) void tail_a(
    const short* __restrict__ h_b, const short* __restrict__ mu_b,   // mu_b padded [112][512]
    const float* __restrict__ feat, const float* __restrict__ hbuf,
    const float* __restrict__ im, const float* __restrict__ q,
    short* __restrict__ dz_b)
{
    __shared__ f32x4 red[4][7][64];
    __shared__ int cstv[16];
    const int tid = threadIdx.x, lane = tid & 63, w = tid >> 6;
    const int m0 = blockIdx.x * 16;
    const int arow = lane & 15, kseg = lane >> 4;

    f32x4 acc[7];
    #pragma unroll
    for (int j = 0; j < 7; ++j) acc[j] = f32x4{0.f, 0.f, 0.f, 0.f};

    const long abase = (long)(m0 + arow) * 512 + w * 128 + kseg * 8;
    const long bbase = (long)arow * 512 + w * 128 + kseg * 8;
    #pragma unroll
    for (int kt = 0; kt < 4; ++kt) {
        s16x8 av = *(const s16x8*)(h_b + abase + kt * 32);
        #pragma unroll
        for (int j = 0; j < 7; ++j) {
            s16x8 bv = *(const s16x8*)(mu_b + bbase + (long)j * 16 * 512 + kt * 32);
            acc[j] = __builtin_amdgcn_mfma_f32_16x16x32_bf16(av, bv, acc[j], 0, 0, 0);
        }
    }
    #pragma unroll
    for (int j = 0; j < 7; ++j) red[w][j][lane] = acc[j];
    __syncthreads();

    if (w == 0) {
        #pragma unroll
        for (int j = 0; j < 7; ++j) {
            f32x4 s0 = red[0][j][lane];
            #pragma unroll
            for (int ww = 1; ww < 4; ++ww) s0 += red[ww][j][lane];
            acc[j] = s0;
        }
        const int crow = (lane >> 4) * 4, ccol = lane & 15;
        #pragma unroll
        for (int r = 0; r < 4; ++r) {
            float best = -INFINITY; int bestc = 0;
            #pragma unroll
            for (int j = 0; j < 7; ++j) {
                int n = j * 16 + ccol;
                if (n < 100) {
                    float v = 2.f * acc[j][r] - q[n];
                    if (v > best) { best = v; bestc = n; }
                }
            }
            #pragma unroll
            for (int mk = 1; mk <= 8; mk <<= 1) {
                float ov = __shfl_xor(best, mk);
                int   oc = __shfl_xor(bestc, mk);
                if (ov > best || (ov == best && oc < bestc)) { best = ov; bestc = oc; }
            }
            if (ccol == 0) cstv[crow + r] = bestc;
        }
    }
    __syncthreads();

    // dz: 16 rows x 512 = 2048 f32x4 quads, 8 per thread, independent iterations
    #pragma unroll
    for (int it = 0; it < 8; ++it) {
        int i4 = it * 256 + tid;
        int r = i4 >> 7, d4 = (i4 & 127) * 4;
        long gi = (long)(m0 + r) * 512 + d4;
        f32x4 fv = *(const f32x4*)(feat + gi);
        f32x4 hv = *(const f32x4*)(hbuf + gi);
        f32x4 iv = *(const f32x4*)(im + (long)cstv[r] * 512 + d4);
        s16x4 o;
        #pragma unroll
        for (int jj = 0; jj < 4; ++jj) {
            float v = (fv[jj] > 0.f) ? -2.f * (hv[jj] - iv[jj]) : 0.f;
            o[jj] = f2bf(v);
        }
        *(s16x4*)(dz_b + gi) = o;
    }
}

// ---------------- tail B: s = feat.h per row; out = 2*(h@mu^T) - s - q ----------------
__global__ __launch_bounds__(256) void tail_b(
    const short* __restrict__ h_b, const short* __restrict__ mu_b,
    const float* __restrict__ feat, const float* __restrict__ hbuf,
    const float* __restrict__ q, float* __restrict__ out)
{
    __shared__ f32x4 red[4][7][64];
    __shared__ float srow[16];
    const int tid = threadIdx.x, lane = tid & 63, w = tid >> 6;
    const int m0 = blockIdx.x * 16;
    const int arow = lane & 15, kseg = lane >> 4;

    // s for rows w*4 .. w*4+3
    #pragma unroll
    for (int rr = 0; rr < 4; ++rr) {
        int r = w * 4 + rr;
        long gi = (long)(m0 + r) * 512 + lane * 8;
        f32x4 a0 = *(const f32x4*)(feat + gi);
        f32x4 a1 = *(const f32x4*)(feat + gi + 4);
        f32x4 b0 = *(const f32x4*)(hbuf + gi);
        f32x4 b1 = *(const f32x4*)(hbuf + gi + 4);
        float ss = 0.f;
        #pragma unroll
        for (int jj = 0; jj < 4; ++jj) ss += a0[jj] * b0[jj] + a1[jj] * b1[jj];
        #pragma unroll
        for (int off = 32; off; off >>= 1) ss += __shfl_down(ss, off);
        if (lane == 0) srow[r] = ss;
    }

    f32x4 acc[7];
    #pragma unroll
    for (int j = 0; j < 7; ++j) acc[j] = f32x4{0.f, 0.f, 0.f, 0.f};
    const long abase = (long)(m0 + arow) * 512 + w * 128 + kseg * 8;
    const long bbase = (long)arow * 512 + w * 128 + kseg * 8;
    #pragma unroll
    for (int kt = 0; kt < 4; ++kt) {
        s16x8 av = *(const s16x8*)(h_b + abase + kt * 32);
        #pragma unroll
        for (int j = 0; j < 7; ++j) {
            s16x8 bv = *(const s16x8*)(mu_b + bbase + (long)j * 16 * 512 + kt * 32);
            acc[j] = __builtin_amdgcn_mfma_f32_16x16x32_bf16(av, bv, acc[j], 0, 0, 0);
        }
    }
    #pragma unroll
    for (int j = 0; j < 7; ++j) red[w][j][lane] = acc[j];
    __syncthreads();

    if (w == 0) {
        const int crow = (lane >> 4) * 4, ccol = lane & 15;
        #pragma unroll
        for (int j = 0; j < 7; ++j) {
            int n = j * 16 + ccol;
            if (n >= 100) continue;
            f32x4 s0 = red[0][j][lane];
            #pragma unroll
            for (int ww = 1; ww < 4; ++ww) s0 += red[ww][j][lane];
            float qn = q[n];
            #pragma unroll
            for (int r = 0; r < 4; ++r)
                out[(long)(m0 + crow + r) * 100 + n] = 2.f * s0[r] - srow[crow + r] - qn;
        }
    }
}

extern "C" void kernel_launch(void* const* d_in, const int* in_sizes, int n_in,
                              void* d_out, int out_size, void* d_ws, size_t ws_size,
                              hipStream_t stream)
{
    const float* x      = (const float*)d_in[0];
    const float* W      = (const float*)d_in[1];
    const float* bias   = (const float*)d_in[2];
    const float* mu     = (const float*)d_in[3];
    const float* invsig = (const float*)d_in[4];
    float* out = (float*)d_out;

    char* wp = (char*)d_ws;
    auto alloc = [&](size_t bytes) { char* p = wp; wp += (bytes + 255) & ~size_t(255); return p; };
    short* x_b  = (short*)alloc((size_t)Bb * INn * 2);   // reused as xadv bf16
    short* Wt_b = (short*)alloc((size_t)Dd * INn * 2);
    short* W_b  = (short*)alloc((size_t)INn * Dd * 2);
    short* is_b = (short*)alloc((size_t)Dd * Dd * 2);
    short* mu_b = (short*)alloc((size_t)112 * Dd * 2);   // zero-padded to 112 rows
    float* im   = (float*)alloc((size_t)Cc * Dd * 4);
    float* q    = (float*)alloc(512);
    float* part = (float*)alloc((size_t)8 * Bb * Dd * 4);
    float* feat = (float*)alloc((size_t)Bb * Dd * 4);
    short* f_b  = (short*)alloc((size_t)Bb * Dd * 2);
    float* hbuf = (float*)alloc((size_t)Bb * Dd * 4);
    short* h_b  = (short*)alloc((size_t)Bb * Dd * 2);
    short* dz_b = (short*)alloc((size_t)Bb * Dd * 2);

    dim3 blk(256);

    // 1. bf16 planes + W transpose
    prep_kernel<<<512, blk, 0, stream>>>(x, W, invsig, mu, x_b, W_b, Wt_b, is_b, mu_b);
    // 2. im (fp32 exact) + q
    im_q_kernel<<<Cc, blk, 0, stream>>>(mu, invsig, im, q);
    // 3. feat partials: x@W split-K8 (512 blocks)
    gemm_b1<0><<<dim3(Dd / 64, Bb / 128, 8), blk, 0, stream>>>(
        x_b, Wt_b, part, INn, INn / 8, Dd, nullptr, nullptr, 0.f);
    // 4. reduce + bias + relu
    reduce_feat<<<512, blk, 0, stream>>>(part, bias, feat, f_b);
    // 5. h = feat @ invsig
    gemm_b1<1><<<dim3(Dd / 64, Bb / 128, 1), blk, 0, stream>>>(
        f_b, is_b, hbuf, Dd, Dd, Dd, nullptr, h_b, 0.f);
    // 6. t + argmax + dz (64 blocks)
    tail_a<<<Bb / 16, blk, 0, stream>>>(h_b, mu_b, feat, hbuf, im, q, dz_b);
    // 7. xadv = clip(x + eps * dz@W^T) -> x_b
    gemm_b1<2><<<dim3(INn / 64, Bb / 128, 1), blk, 0, stream>>>(
        dz_b, W_b, nullptr, Dd, Dd, INn, x, x_b, EPS_ODIN);
    // 8. feat2 partials
    gemm_b1<0><<<dim3(Dd / 64, Bb / 128, 8), blk, 0, stream>>>(
        x_b, Wt_b, part, INn, INn / 8, Dd, nullptr, nullptr, 0.f);
    // 9. reduce
    reduce_feat<<<512, blk, 0, stream>>>(part, bias, feat, f_b);
    // 10. h2
    gemm_b1<1><<<dim3(Dd / 64, Bb / 128, 1), blk, 0, stream>>>(
        f_b, is_b, hbuf, Dd, Dd, Dd, nullptr, h_b, 0.f);
    // 11. s + out (64 blocks)
    tail_b<<<Bb / 16, blk, 0, stream>>>(h_b, mu_b, feat, hbuf, q, out);
}